// Round 4
// baseline (235.861 us; speedup 1.0000x reference)
//
#include <hip/hip_runtime.h>
#include <hip/hip_fp16.h>
#include <math.h>

// ---------------- problem constants ----------------
#define NB    256
#define NTOKP 197
#define NTOK  196
#define NC    768
#define NHID  192
#define NH    14
#define NVF   8        // rfft cols = 14/2+1
#define CHT   64       // channels per tile
#define NTILE 12       // 768/64
#define HPB   4        // hiddens per block in k_mlp1

// twiddles (compile-time folded under full unroll)
constexpr float CT14[14] = {
    1.0f, 0.9009688679024191f, 0.6234898018587336f, 0.22252093395631445f,
    -0.22252093395631434f, -0.6234898018587335f, -0.9009688679024191f, -1.0f,
    -0.9009688679024191f, -0.6234898018587335f, -0.22252093395631434f,
    0.22252093395631445f, 0.6234898018587336f, 0.9009688679024191f};
constexpr float ST14[14] = {
    0.0f, 0.4338837391175581f, 0.7818314824680298f, 0.9749279121818236f,
    0.9749279121818236f, 0.7818314824680299f, 0.43388373911755823f, 0.0f,
    -0.43388373911755823f, -0.7818314824680299f, -0.9749279121818236f,
    -0.9749279121818236f, -0.7818314824680298f, -0.4338837391175581f};
constexpr float C7[7] = {1.0f, 0.6234898018587336f, -0.22252093395631434f,
                         -0.9009688679024191f, -0.9009688679024191f,
                         -0.22252093395631434f, 0.6234898018587336f};
constexpr float S7[7] = {0.0f, 0.7818314824680298f, 0.9749279121818236f,
                         0.4338837391175581f, -0.4338837391175581f,
                         -0.9749279121818236f, -0.7818314824680298f};

__device__ __forceinline__ unsigned int pack_h2(float a, float b) {
  __half2 h = __floats2half2_rn(a, b);
  return *(unsigned int*)&h;
}
__device__ __forceinline__ float2 unpack_h2(unsigned int p) {
  __half2 h = *(__half2*)&p;
  return __half22float2(h);
}

// ---------------- K1: LN stats (+ optional fp16 xn write) ----------------
template <bool WH>
__global__ __launch_bounds__(256) void k_stats(const float* __restrict__ x,
                                               const float* __restrict__ gamma,
                                               const float* __restrict__ beta,
                                               float2* __restrict__ msv,
                                               __half* __restrict__ xnh) {
  int row = blockIdx.x * 4 + (threadIdx.x >> 6);
  int lane = threadIdx.x & 63;
  int b = row / NTOK, t = row - b * NTOK;
  const float4* p = (const float4*)(x + ((size_t)b * NTOKP + 1 + t) * NC);
  float4 v[3];
  float s = 0.f, ss = 0.f;
#pragma unroll
  for (int k = 0; k < 3; ++k) {
    v[k] = p[lane + k * 64];
    s += v[k].x + v[k].y + v[k].z + v[k].w;
    ss += v[k].x * v[k].x + v[k].y * v[k].y + v[k].z * v[k].z + v[k].w * v[k].w;
  }
#pragma unroll
  for (int m = 32; m; m >>= 1) {
    s += __shfl_xor(s, m);
    ss += __shfl_xor(ss, m);
  }
  float mean = s * (1.f / NC);
  float var = ss * (1.f / NC) - mean * mean;
  float rstd = rsqrtf(var + 1e-5f);
  if (lane == 0) msv[row] = make_float2(mean, rstd);
  if (WH) {
#pragma unroll
    for (int k = 0; k < 3; ++k) {
      float4 g = ((const float4*)gamma)[lane + k * 64];
      float4 be = ((const float4*)beta)[lane + k * 64];
      float4 xn;
      xn.x = (v[k].x - mean) * rstd * g.x + be.x;
      xn.y = (v[k].y - mean) * rstd * g.y + be.y;
      xn.z = (v[k].z - mean) * rstd * g.z + be.z;
      xn.w = (v[k].w - mean) * rstd * g.w + be.w;
      uint2 u = make_uint2(pack_h2(xn.x, xn.y), pack_h2(xn.z, xn.w));
      *(uint2*)(xnh + (size_t)row * NC + lane * 4 + k * 256) = u;
    }
  }
}

// ---------------- K2: forward DFT + energy (transposed out) ----------------
template <bool UH>
__global__ __launch_bounds__(256) void k_fwd(const float* __restrict__ x,
                                             const __half* __restrict__ xnh,
                                             const float* __restrict__ gamma,
                                             const float* __restrict__ beta,
                                             const float2* __restrict__ msv,
                                             float* __restrict__ energy_t) {
  __shared__ unsigned int A[NH * NVF * CHT];  // [i][v][c] packed fp16 28.7KB
  __shared__ float esum[256];
  __shared__ float2 ms[UH ? 1 : NTOK];
  int b = blockIdx.y, c0 = blockIdx.x * CHT, tid = threadIdx.x;
  int c = tid & 63, w = tid >> 6;

  float g = 0.f, be = 0.f;
  if (!UH) {
    for (int k = tid; k < NTOK; k += 256) ms[k] = msv[b * NTOK + k];
    g = gamma[c0 + c];
    be = beta[c0 + c];
    __syncthreads();
  }

  // stage A: per (c,i): A[i,v] = sum_j xn[i,j] e^{-2pi i v j/14}
#pragma unroll 1
  for (int i = w; i < NH; i += 4) {
    float xn_[NH];
    if (UH) {
      const __half* xr = xnh + ((size_t)b * NTOK + i * NH) * NC + c0 + c;
#pragma unroll
      for (int j = 0; j < NH; ++j) xn_[j] = __half2float(xr[j * NC]);
    } else {
      const float* xr = x + ((size_t)b * NTOKP + 1 + i * NH) * NC + c0 + c;
#pragma unroll
      for (int j = 0; j < NH; ++j) {
        float2 m = ms[i * NH + j];
        xn_[j] = (xr[(size_t)j * NC] - m.x) * m.y * g + be;
      }
    }
    float ar[NVF] = {}, ai[NVF] = {};
#pragma unroll
    for (int j = 0; j < NH; ++j) {
#pragma unroll
      for (int v = 0; v < NVF; ++v) {
        ar[v] = fmaf(xn_[j], CT14[(v * j) % 14], ar[v]);
        ai[v] = fmaf(-xn_[j], ST14[(v * j) % 14], ai[v]);
      }
    }
#pragma unroll
    for (int v = 0; v < NVF; ++v) A[(i * NVF + v) * CHT + c] = pack_h2(ar[v], ai[v]);
  }
  __syncthreads();

  // stage B (radix-2 over rows): per (c, v in {2w,2w+1})
  float part = 0.f;
#pragma unroll 1
  for (int vv = 0; vv < 2; ++vv) {
    int v = w * 2 + vv;
    const unsigned int* Ac = A + v * CHT + c;
    float er[7], ei[7], orr[7], oii[7];
#pragma unroll
    for (int k = 0; k < 7; ++k) { er[k] = 0.f; ei[k] = 0.f; orr[k] = 0.f; oii[k] = 0.f; }
#pragma unroll
    for (int m = 0; m < 7; ++m) {
      float2 ae = unpack_h2(Ac[(2 * m) * NVF * CHT]);
      float2 ao = unpack_h2(Ac[(2 * m + 1) * NVF * CHT]);
#pragma unroll
      for (int k = 0; k < 7; ++k) {
        int t = (k * m) % 7;
        er[k] = fmaf(ae.x, C7[t], fmaf(ae.y, S7[t], er[k]));
        ei[k] = fmaf(ae.y, C7[t], fmaf(-ae.x, S7[t], ei[k]));
        orr[k] = fmaf(ao.x, C7[t], fmaf(ao.y, S7[t], orr[k]));
        oii[k] = fmaf(ao.y, C7[t], fmaf(-ao.x, S7[t], oii[k]));
      }
    }
#pragma unroll
    for (int u = 0; u < NH; ++u) {
      int k = u % 7;
      float tr = fmaf(orr[k], CT14[u], oii[k] * ST14[u]);
      float ti = fmaf(oii[k], CT14[u], -orr[k] * ST14[u]);
      float sr = er[k] + tr, si = ei[k] + ti;
      float m2 = fmaf(sr, sr, si * si);
      float lg = __logf(1.f + __builtin_amdgcn_sqrtf(m2) * (1.f / 14.f));
      if (u == 0) {
        if (v != 0) part += lg;  // DC bin excluded (zero-mean input)
      } else {
        part += lg;
      }
    }
  }
  esum[tid] = part;
  __syncthreads();
  if (w == 0) {
    float e = esum[c] + esum[c + 64] + esum[c + 128] + esum[c + 192];
    energy_t[(size_t)(c0 + c) * NB + b] = e * (1.f / 112.f);
  }
}

// ---------------- K3a: layer 1 (batch = lane axis, coalesced) ----------------
__global__ __launch_bounds__(256) void k_mlp1(const float* __restrict__ et,
                                              const float* __restrict__ w1,
                                              const float* __restrict__ b1,
                                              float* __restrict__ hdt) {
  int h0 = blockIdx.x * HPB;
  int bb = threadIdx.x;  // batch
  float acc[HPB];
#pragma unroll
  for (int k = 0; k < HPB; ++k) acc[k] = b1[h0 + k];
#pragma unroll 8
  for (int cc = 0; cc < NC; ++cc) {
    float e = et[(size_t)cc * NB + bb];
#pragma unroll
    for (int k = 0; k < HPB; ++k)
      acc[k] = fmaf(e, w1[cc * NHID + h0 + k], acc[k]);
  }
#pragma unroll
  for (int k = 0; k < HPB; ++k) {
    float a = acc[k];
    float ge = 0.5f * a * (1.f + erff(a * 0.70710678118654752f));
    hdt[(size_t)(h0 + k) * NB + bb] = ge;
  }
}

// ---------------- K3b: layer 2 + mask params ----------------
__global__ __launch_bounds__(256) void k_mlp2(const float* __restrict__ hdt,
                                              const float* __restrict__ w2,
                                              const float* __restrict__ b2,
                                              float* __restrict__ m2s) {
  int bb = threadIdx.x;
  float a0 = b2[0], a1 = b2[1];
#pragma unroll 8
  for (int h = 0; h < NHID; ++h) {
    float hv = hdt[(size_t)h * NB + bb];
    a0 = fmaf(hv, w2[2 * h], a0);
    a1 = fmaf(hv, w2[2 * h + 1], a1);
  }
  float muv = 9.899494936611665f / (1.f + expf(-a0));
  muv = fmaxf(muv, 1.f);
  float sp = (a1 > 20.f) ? a1 : log1pf(expf(a1));
  float sg = fmaxf(sp, 0.1f);
  m2s[bb] = 2.f * muv * muv * sg + 1e-6f;
}

// ---------------- K4: separable circulant filter + residual ----------------
// filtered = K (x) K (x) xn   (mean drops out: mask[0,0]=1)
// xv reconstructed from fp16 xn: xv = (xn-beta)/(gamma*rstd)+mean
template <bool UH>
__global__ __launch_bounds__(256) void k_inv(const float* __restrict__ x,
                                             const __half* __restrict__ xnh,
                                             const float* __restrict__ gamma,
                                             const float* __restrict__ beta,
                                             const float2* __restrict__ msv,
                                             const float* __restrict__ m2s,
                                             const float* __restrict__ rscale,
                                             float* __restrict__ out) {
  __shared__ unsigned int T[NH * 7 * CHT];          // y fp16 pairs   25KB
  __shared__ unsigned int X[UH ? 1 : NH * 7 * CHT]; // xn fp16 pairs (fallback)
  __shared__ float2 ms[NTOK];
  __shared__ float rr[NTOK];
  __shared__ float wexp[NH];
  __shared__ float kcs[NH];
  int b = blockIdx.y, c0 = blockIdx.x * CHT, tid = threadIdx.x;
  int c = tid & 63, w = tid >> 6;
  float rs = rscale[0];

  for (int k = tid; k < NTOK; k += 256) {
    float2 m = msv[b * NTOK + k];
    ms[k] = m;
    rr[k] = 1.f / m.y;
  }
  if (tid < CHT) {  // cls-token passthrough
    size_t idx = (size_t)b * NTOKP * NC + c0 + tid;
    out[idx] = x[idx];
  }
  float msb = m2s[b];
  if (tid < NH) {
    int f = (tid <= 7) ? tid : 14 - tid;
    wexp[tid] = __expf(-(float)(f * f) / msb);
  }
  __syncthreads();
  if (tid < NH) {
    float s = 0.f;
#pragma unroll
    for (int k = 0; k < NH; ++k) s = fmaf(wexp[k], CT14[(k * tid) % 14], s);
    kcs[tid] = s * (1.f / 14.f);
  }
  float g = gamma[c0 + c], be = beta[c0 + c];
  float rg = 1.f / g;
  __syncthreads();

  float kr[NH];
#pragma unroll
  for (int d = 0; d < NH; ++d) kr[d] = kcs[d];

  // stage 1: y[i,j'] = sum_j xn[i,j]*kc[(j'-j)%14] -> T
#pragma unroll 1
  for (int i = w; i < NH; i += 4) {
    float xn_[NH];
    if (UH) {
      const __half* xr = xnh + ((size_t)b * NTOK + i * NH) * NC + c0 + c;
#pragma unroll
      for (int j = 0; j < NH; ++j) xn_[j] = __half2float(xr[j * NC]);
    } else {
      const float* xr = x + ((size_t)b * NTOKP + 1 + i * NH) * NC + c0 + c;
#pragma unroll
      for (int j = 0; j < NH; ++j) {
        float2 m = ms[i * NH + j];
        xn_[j] = (xr[(size_t)j * NC] - m.x) * m.y * g + be;
      }
#pragma unroll
      for (int k = 0; k < 7; ++k)
        X[(i * 7 + k) * CHT + c] = pack_h2(xn_[2 * k], xn_[2 * k + 1]);
    }
#pragma unroll
    for (int jp = 0; jp < 7; ++jp) {
      float y0 = 0.f, y1 = 0.f;
#pragma unroll
      for (int j = 0; j < NH; ++j) {
        y0 = fmaf(xn_[j], kr[(2 * jp - j + 28) % 14], y0);
        y1 = fmaf(xn_[j], kr[(2 * jp + 1 - j + 28) % 14], y1);
      }
      T[(i * 7 + jp) * CHT + c] = pack_h2(y0, y1);
    }
  }
  __syncthreads();

  // stage 2: z[i'] = sum_i y[i,jq]*kc[(i'-i)%14]; out = xv + rs*(z-xn)
#pragma unroll 1
  for (int jq = w; jq < NH; jq += 4) {
    int jp = jq >> 1, hi = jq & 1;
    float y[NH];
#pragma unroll
    for (int i = 0; i < NH; ++i) {
      float2 v = unpack_h2(T[(i * 7 + jp) * CHT + c]);
      y[i] = hi ? v.y : v.x;
    }
    const __half* xq = xnh + ((size_t)b * NTOK + jq) * NC + c0 + c;
    float* outr = out + ((size_t)b * NTOKP + 1 + jq) * NC + c0 + c;
#pragma unroll
    for (int ii = 0; ii < NH; ++ii) {
      float z = 0.f;
#pragma unroll
      for (int i = 0; i < NH; ++i) z = fmaf(y[i], kr[(ii - i + 28) % 14], z);
      float xnv;
      if (UH) {
        xnv = __half2float(xq[(size_t)ii * NH * NC]);
      } else {
        float2 v = unpack_h2(X[(ii * 7 + jp) * CHT + c]);
        xnv = hi ? v.y : v.x;
      }
      int t = ii * NH + jq;
      float xv = fmaf((xnv - be) * rg, rr[t], ms[t].x);
      outr[(size_t)ii * NH * NC] = xv + rs * (z - xnv);
    }
  }
}

extern "C" void kernel_launch(void* const* d_in, const int* in_sizes, int n_in,
                              void* d_out, int out_size, void* d_ws, size_t ws_size,
                              hipStream_t stream) {
  (void)in_sizes; (void)n_in; (void)out_size;
  const float* x      = (const float*)d_in[0];
  const float* gamma  = (const float*)d_in[1];
  const float* beta   = (const float*)d_in[2];
  const float* w1     = (const float*)d_in[3];
  const float* b1     = (const float*)d_in[4];
  const float* w2     = (const float*)d_in[5];
  const float* b2     = (const float*)d_in[6];
  const float* rscale = (const float*)d_in[7];
  float* out = (float*)d_out;

  char* wsb = (char*)d_ws;
  float2* msv     = (float2*)(wsb + 0);        //   401,408 B
  float* energy_t = (float*)(wsb + 401408);    //   786,432 B
  float* hdt      = (float*)(wsb + 1187840);   //   196,608 B
  float* m2s      = (float*)(wsb + 1384448);   //     1,024 B
  __half* xnh     = (__half*)(wsb + 1385984);  // 77,070,336 B
  size_t need = 1385984 + (size_t)NB * NTOK * NC * 2;
  bool useH = ws_size >= need;

  if (useH) {
    k_stats<true><<<NB * NTOK / 4, 256, 0, stream>>>(x, gamma, beta, msv, xnh);
    k_fwd<true><<<dim3(NTILE, NB), 256, 0, stream>>>(x, xnh, gamma, beta, msv,
                                                     energy_t);
  } else {
    k_stats<false><<<NB * NTOK / 4, 256, 0, stream>>>(x, gamma, beta, msv, xnh);
    k_fwd<false><<<dim3(NTILE, NB), 256, 0, stream>>>(x, xnh, gamma, beta, msv,
                                                      energy_t);
  }
  k_mlp1<<<NHID / HPB, 256, 0, stream>>>(energy_t, w1, b1, hdt);
  k_mlp2<<<1, 256, 0, stream>>>(hdt, w2, b2, m2s);
  if (useH) {
    k_inv<true><<<dim3(NTILE, NB), 256, 0, stream>>>(x, xnh, gamma, beta, msv,
                                                     m2s, rscale, out);
  } else {
    k_inv<false><<<dim3(NTILE, NB), 256, 0, stream>>>(x, xnh, gamma, beta, msv,
                                                      m2s, rscale, out);
  }
}